// Round 8
// baseline (113.717 us; speedup 1.0000x reference)
//
#include <hip/hip_runtime.h>
#include <math.h>

#define RES_W 256
#define RES_H 256
#define TF_RES 128

typedef float float2u __attribute__((ext_vector_type(2), aligned(4)));

// One wave = 2 rays; lanes 0-31 march samples of ray A, lanes 32-63 ray B.
// Transmittance via 32-wide product-scan; rgb/acc/first-hit reduced once at end.
// __launch_bounds__(256,4): VGPR cap 128 — demand is ~90, so NO scratch spills
// (the (256,8) cap of 64 VGPRs forced inner-loop spills — the R6/R7 31us wall).
__global__ __launch_bounds__(256, 4) void raycast_kernel(
    const float* __restrict__ vol,    // [256,256,256] x-major: idx = (x<<16)+(y<<8)+z
    const float* __restrict__ tf,     // [128,4]
    const float* __restrict__ cam_p,  // [3]
    const int*   __restrict__ sr_p,   // [1]
    float* __restrict__ out)          // [256,256,5]  idx = (w*256+h)*5+c
{
    #pragma clang fp contract(off)

    // 129-entry SoA tables: [128] duplicates [127] so (lo, lo+1) is always a
    // valid adjacent-dword pair -> ds_read2_b32, exact for the lo==127 edge.
    __shared__ float tfR[TF_RES + 1], tfG[TF_RES + 1], tfB[TF_RES + 1], tfA[TF_RES + 1];
    const int tid = (int)threadIdx.x;   // 0..255
    if (tid < TF_RES) {
        float4 e = ((const float4*)tf)[tid];
        tfR[tid] = e.x; tfG[tid] = e.y; tfB[tid] = e.z; tfA[tid] = e.w;
        if (tid == TF_RES - 1) {
            tfR[TF_RES] = e.x; tfG[TF_RES] = e.y; tfB[TF_RES] = e.z; tfA[TF_RES] = e.w;
        }
    }
    __syncthreads();

    const int lane = tid & 63;
    const int sub  = lane & 31;         // position within this ray's 32-lane half

    // 8192 blocks x 8 rays. XCD swizzle: block b -> XCD b%8 gets contiguous slab.
    const int b  = (int)blockIdx.x;
    const int sb = (b & 7) * 1024 + (b >> 3);
    const int ray = sb * 8 + (tid >> 5);      // 0..65535, h-major
    const int h = ray & 255;                  // H index (v axis)
    const int w = ray >> 8;                   // W index (u axis)

    const float cx = cam_p[0], cy = cam_p[1], cz = cam_p[2];
    const int   sr_i = sr_p[0];
    const float srf = (float)sr_i;

    // ---- camera basis, fp32, numpy op order, no FMA (bit-matches reference) ----
    float nx = -cx, ny = -cy, nz = -cz;
    float fl = __fsqrt_rn((nx*nx + ny*ny) + nz*nz);
    float fx = nx / fl, fy = ny / fl, fz = nz / fl;
    float rxu = 0.0f - fz;
    float rzu = fx;
    float rl = __fsqrt_rn((rxu*rxu + 0.0f) + rzu*rzu);
    float rx = rxu / rl, rz = rzu / rl;
    float ux = 0.0f - rz*fy;
    float uy = rz*fx - rx*fz;
    float uz = rx*fy;

    const float ang32 = (float)((30.0 * 0.017453292519943295) * 0.5);
    const float tan_half = (float)tan((double)ang32);

    float uu = ((((float)w + 0.5f) / 256.0f) * 2.0f - 1.0f) * tan_half;
    float vv = ((((float)h + 0.5f) / 256.0f) * 2.0f - 1.0f) * tan_half;

    float dx = (fx + uu*rx) + vv*ux;
    float dy = (fy + 0.0f ) + vv*uy;
    float dz = (fz + uu*rz) + vv*uz;
    float dl = __fsqrt_rn((dx*dx + dy*dy) + dz*dz);
    dx = dx / dl; dy = dy / dl; dz = dz / dl;

    float ivx = 1.0f/dx, ivy = 1.0f/dy, ivz = 1.0f/dz;
    float tlx = (-1.0f - cx)*ivx, thx = (1.0f - cx)*ivx;
    float tly = (-1.0f - cy)*ivy, thy = (1.0f - cy)*ivy;
    float tlz = (-1.0f - cz)*ivz, thz = (1.0f - cz)*ivz;
    float tmin = fmaxf(fmaxf(fminf(tlx,thx), fminf(tly,thy)), fminf(tlz,thz));
    float tmax = fminf(fminf(fmaxf(tlx,thx), fmaxf(tly,thy)), fmaxf(tlz,thz));
    bool hit = (tmax >= 0.0f) && (tmin <= tmax);

    float entry = fmaxf(tmin, 0.1f);
    float dist  = hit ? fmaxf(tmax - entry, 0.0f) : 0.0f;
    float nsf   = fminf(fmaxf(ceilf(((dist * 0.5f) * 256.0f) * srf), 1.0f), 384.0f);
    int   ns    = (int)nsf;
    float step  = dist / nsf;

    float rgb_r = 0.0f, rgb_g = 0.0f, rgb_b = 0.0f, acc = 0.0f;  // per-lane partials
    float T_prev = 1.0f;          // transmittance entering current chunk (per ray)
    int   hk_min = 0x7FFFFFFF;    // per-lane first-hit sample index

    for (int base = 0; ; ) {
        const int  k     = base + sub;
        const bool valid = hit && (k < ns);

        // ---- per-lane sample: position + 4 float2 z-pair gathers ----
        float t  = entry + ((float)k + 0.5f) * step;
        float px = (cx + t*dx);
        float py = (cy + t*dy);
        float pz = (cz + t*dz);
        px = ((px * 0.5f) + 0.5f) * 255.0f;
        py = ((py * 0.5f) + 0.5f) * 255.0f;
        pz = ((pz * 0.5f) + 0.5f) * 255.0f;
        px = fminf(fmaxf(px, 0.0f), 255.0f);
        py = fminf(fmaxf(py, 0.0f), 255.0f);
        pz = fminf(fmaxf(pz, 0.0f), 255.0f);
        int x0 = (int)floorf(px), y0 = (int)floorf(py), z0 = (int)floorf(pz);
        float ffx = px - (float)x0;
        float ffy = py - (float)y0;
        float ffz = pz - (float)z0;
        int x1 = min(x0 + 1, 255);
        int y1 = min(y0 + 1, 255);
        int zb = min(z0, 254);               // pair base; z0==255 -> ffz==0 exactly
        int bx0 = x0 << 16, bx1 = x1 << 16;
        int by0 = y0 << 8,  by1 = y1 << 8;
        float2u p00 = *(const float2u*)(vol + (bx0 + by0 + zb));
        float2u p10 = *(const float2u*)(vol + (bx1 + by0 + zb));
        float2u p01 = *(const float2u*)(vol + (bx0 + by1 + zb));
        float2u p11 = *(const float2u*)(vol + (bx1 + by1 + zb));
        // z0==255 (only when pz==255.0, ffz==0): tap0 must read index 255 = pair.y
        if (z0 == 255) {
            p00.x = p00.y; p10.x = p10.y; p01.x = p01.y; p11.x = p11.y;
        }

        float omx = 1.0f - ffx, omy = 1.0f - ffy, omz = 1.0f - ffz;
        float c00 = p00.x*omx + p10.x*ffx;
        float c10 = p01.x*omx + p11.x*ffx;
        float c01 = p00.y*omx + p10.y*ffx;
        float c11 = p01.y*omx + p11.y*ffx;
        float c0  = c00*omy + c10*ffy;
        float c1  = c01*omy + c11*ffy;
        float intensity = c0*omz + c1*ffz;

        // ---- TF lookup: adjacent-pair LDS reads (ds_read2_b32) ----
        float xi = fminf(fmaxf(intensity, 0.0f), 1.0f) * 127.0f;
        int lo  = (int)floorf(xi);
        float tfr = xi - (float)lo;
        float omt = 1.0f - tfr;
        float cr  = tfR[lo]*omt + tfR[lo + 1]*tfr;
        float cg  = tfG[lo]*omt + tfG[lo + 1]*tfr;
        float cbb = tfB[lo]*omt + tfB[lo + 1]*tfr;
        float a   = tfA[lo]*omt + tfA[lo + 1]*tfr;

        if (sr_i == 1) {
            a = 1.0f - (1.0f - a);               // double rounding, as numpy
        } else {
            a = 1.0f - powf(1.0f - a, 1.0f / srf);
        }
        if (!valid) a = 0.0f;                    // reference: a = where(valid, a, 0)
        float one_m = 1.0f - a;

        // ---- 32-wide inclusive product scan of one_m (Hillis-Steele) ----
        float x = one_m;
        #pragma unroll
        for (int off = 1; off < 32; off <<= 1) {
            float y = __shfl_up(x, off);
            if (sub >= off) x *= y;
        }
        float ex = __shfl_up(x, 1);
        if (sub == 0) ex = 1.0f;                 // exclusive transmittance within chunk

        float wgt = (T_prev * ex) * a;
        rgb_r += wgt * cr;
        rgb_g += wgt * cg;
        rgb_b += wgt * cbb;
        acc   += wgt;
        if (valid && (a > 1e-3f)) hk_min = min(hk_min, k);

        // ---- chunk carry ----
        float Tc = __shfl(x, (lane & 32) | 31);  // inclusive product at end of half
        T_prev = T_prev * Tc;

        base += 32;
        // T<1e-7 implies some a>1e-3; truncation err <= 1e-7
        bool active = hit && (base < ns) && (T_prev >= 1e-7f);
        if (__ballot(active) == 0ULL) break;
    }

    // ---- final reductions within each 32-lane half ----
    #pragma unroll
    for (int m = 16; m >= 1; m >>= 1) {
        rgb_r += __shfl_xor(rgb_r, m);
        rgb_g += __shfl_xor(rgb_g, m);
        rgb_b += __shfl_xor(rgb_b, m);
        acc   += __shfl_xor(acc,   m);
        hk_min = min(hk_min, __shfl_xor(hk_min, m));
    }

    if (sub == 0) {
        float depth = 1.0f;
        if (hk_min != 0x7FFFFFFF) {
            float tfh = entry + ((float)hk_min + 0.5f) * step;  // same expr as reference
            depth = (tfh - 0.1f) / 99.9f;
        }
        int oi = (w * RES_H + h) * 5;
        out[oi + 0] = rgb_r;
        out[oi + 1] = rgb_g;
        out[oi + 2] = rgb_b;
        out[oi + 3] = acc;
        out[oi + 4] = depth;
    }
}

extern "C" void kernel_launch(void* const* d_in, const int* in_sizes, int n_in,
                              void* d_out, int out_size, void* d_ws, size_t ws_size,
                              hipStream_t stream) {
    const float* vol = (const float*)d_in[0];
    const float* tf  = (const float*)d_in[1];
    const float* cam = (const float*)d_in[2];
    const int*   sr  = (const int*)d_in[3];
    float* out = (float*)d_out;

    // 65536 rays, 2 rays/wave, 4 waves/block -> 8192 blocks
    raycast_kernel<<<dim3(8192), dim3(256), 0, stream>>>(vol, tf, cam, sr, out);
}

// Round 9
// 103.363 us; speedup vs baseline: 1.1002x; 1.1002x over previous
//
#include <hip/hip_runtime.h>
#include <math.h>

#define RES_W 256
#define RES_H 256
#define TF_RES 128

typedef float float2u __attribute__((ext_vector_type(2), aligned(4)));

// ---------- pass 1: per-ray setup (bit-exact basis / entry / step / ns) ----------
__global__ __launch_bounds__(256) void ray_setup_kernel(
    const float* __restrict__ cam_p,
    const int*   __restrict__ sr_p,
    float* __restrict__ rws)            // [65536][8]: dx,dy,dz,entry | step,nsf,hitf,0
{
    #pragma clang fp contract(off)
    const int ray = (int)blockIdx.x * 256 + (int)threadIdx.x;
    const int h = ray & 255;
    const int w = ray >> 8;

    const float cx = cam_p[0], cy = cam_p[1], cz = cam_p[2];
    const float srf = (float)sr_p[0];

    float nx = -cx, ny = -cy, nz = -cz;
    float fl = __fsqrt_rn((nx*nx + ny*ny) + nz*nz);
    float fx = nx / fl, fy = ny / fl, fz = nz / fl;
    float rxu = 0.0f - fz;
    float rzu = fx;
    float rl = __fsqrt_rn((rxu*rxu + 0.0f) + rzu*rzu);
    float rx = rxu / rl, rz = rzu / rl;
    float ux = 0.0f - rz*fy;
    float uy = rz*fx - rx*fz;
    float uz = rx*fy;

    const float ang32 = (float)((30.0 * 0.017453292519943295) * 0.5);
    const float tan_half = (float)tan((double)ang32);

    float uu = ((((float)w + 0.5f) / 256.0f) * 2.0f - 1.0f) * tan_half;
    float vv = ((((float)h + 0.5f) / 256.0f) * 2.0f - 1.0f) * tan_half;

    float dx = (fx + uu*rx) + vv*ux;
    float dy = (fy + 0.0f ) + vv*uy;
    float dz = (fz + uu*rz) + vv*uz;
    float dl = __fsqrt_rn((dx*dx + dy*dy) + dz*dz);
    dx = dx / dl; dy = dy / dl; dz = dz / dl;

    float ivx = 1.0f/dx, ivy = 1.0f/dy, ivz = 1.0f/dz;
    float tlx = (-1.0f - cx)*ivx, thx = (1.0f - cx)*ivx;
    float tly = (-1.0f - cy)*ivy, thy = (1.0f - cy)*ivy;
    float tlz = (-1.0f - cz)*ivz, thz = (1.0f - cz)*ivz;
    float tmin = fmaxf(fmaxf(fminf(tlx,thx), fminf(tly,thy)), fminf(tlz,thz));
    float tmax = fminf(fminf(fmaxf(tlx,thx), fmaxf(tly,thy)), fmaxf(tlz,thz));
    bool hit = (tmax >= 0.0f) && (tmin <= tmax);

    float entry = fmaxf(tmin, 0.1f);
    float dist  = hit ? fmaxf(tmax - entry, 0.0f) : 0.0f;
    float nsf   = fminf(fmaxf(ceilf(((dist * 0.5f) * 256.0f) * srf), 1.0f), 384.0f);
    float step  = dist / nsf;

    float4* o = (float4*)(rws + (size_t)ray * 8);
    o[0] = make_float4(dx, dy, dz, entry);
    o[1] = make_float4(step, nsf, hit ? 1.0f : 0.0f, 0.0f);
}

// ---------- pass 2: march. 16 lanes per ray, 4 rays/wave, chunk = 16 samples ----------
__global__ __launch_bounds__(256) void raycast_kernel(
    const float* __restrict__ vol,    // [256,256,256] x-major: idx = (x<<16)+(y<<8)+z
    const float* __restrict__ tf,     // [128,4]
    const float* __restrict__ cam_p,  // [3]
    const int*   __restrict__ sr_p,   // [1]
    const float* __restrict__ rws,    // per-ray setup from pass 1
    float* __restrict__ out)          // [256,256,5]
{
    #pragma clang fp contract(off)

    __shared__ float tfR[TF_RES + 1], tfG[TF_RES + 1], tfB[TF_RES + 1], tfA[TF_RES + 1];
    const int tid = (int)threadIdx.x;   // 0..255
    if (tid < TF_RES) {
        float4 e = ((const float4*)tf)[tid];
        tfR[tid] = e.x; tfG[tid] = e.y; tfB[tid] = e.z; tfA[tid] = e.w;
        if (tid == TF_RES - 1) {
            tfR[TF_RES] = e.x; tfG[TF_RES] = e.y; tfB[TF_RES] = e.z; tfA[TF_RES] = e.w;
        }
    }
    __syncthreads();

    const int lane = tid & 63;
    const int sub  = lane & 15;                // position within this ray's 16 lanes

    // 4096 blocks x 16 rays. XCD swizzle: block b -> XCD b%8 gets contiguous slab.
    const int b  = (int)blockIdx.x;
    const int sb = (b & 7) * 512 + (b >> 3);   // 0..4095
    const int ray = sb * 16 + (tid >> 4);      // 0..65535, h-major
    const int h = ray & 255;
    const int w = ray >> 8;

    const float cx = cam_p[0], cy = cam_p[1], cz = cam_p[2];
    const int   sr_i = sr_p[0];
    const float srf = (float)sr_i;

    const float4* rp = (const float4*)(rws + (size_t)ray * 8);
    float4 ra = rp[0];                          // dx,dy,dz,entry
    float4 rb = rp[1];                          // step,nsf,hitf
    const float dx = ra.x, dy = ra.y, dz = ra.z, entry = ra.w;
    const float step = rb.x;
    const int   ns   = (int)rb.y;
    const bool  hit  = (rb.z != 0.0f);

    float rgb_r = 0.0f, rgb_g = 0.0f, rgb_b = 0.0f, acc = 0.0f;  // per-lane partials
    float T_prev = 1.0f;          // ray transmittance entering current chunk
    int   hk_min = 0x7FFFFFFF;    // per-lane first-hit sample index

    for (int base = 0; ; ) {
        const int  k     = base + sub;
        const bool valid = hit && (k < ns);

        // ---- per-lane sample (bit-exact reference op order) ----
        float t  = entry + ((float)k + 0.5f) * step;
        float px = (cx + t*dx);
        float py = (cy + t*dy);
        float pz = (cz + t*dz);
        px = ((px * 0.5f) + 0.5f) * 255.0f;
        py = ((py * 0.5f) + 0.5f) * 255.0f;
        pz = ((pz * 0.5f) + 0.5f) * 255.0f;
        px = fminf(fmaxf(px, 0.0f), 255.0f);
        py = fminf(fmaxf(py, 0.0f), 255.0f);
        pz = fminf(fmaxf(pz, 0.0f), 255.0f);
        int x0 = (int)floorf(px), y0 = (int)floorf(py), z0 = (int)floorf(pz);
        float ffx = px - (float)x0;
        float ffy = py - (float)y0;
        float ffz = pz - (float)z0;
        int x1 = min(x0 + 1, 255);
        int y1 = min(y0 + 1, 255);
        int zb = min(z0, 254);               // z-pair base; z0==255 -> ffz==0 exactly
        int bx0 = x0 << 16, bx1 = x1 << 16;
        int by0 = y0 << 8,  by1 = y1 << 8;
        float2u p00 = *(const float2u*)(vol + (bx0 + by0 + zb));
        float2u p10 = *(const float2u*)(vol + (bx1 + by0 + zb));
        float2u p01 = *(const float2u*)(vol + (bx0 + by1 + zb));
        float2u p11 = *(const float2u*)(vol + (bx1 + by1 + zb));
        if (z0 == 255) {                     // tap z0 must read index 255 = pair.y
            p00.x = p00.y; p10.x = p10.y; p01.x = p01.y; p11.x = p11.y;
        }

        float omx = 1.0f - ffx, omy = 1.0f - ffy, omz = 1.0f - ffz;
        float c00 = p00.x*omx + p10.x*ffx;
        float c10 = p01.x*omx + p11.x*ffx;
        float c01 = p00.y*omx + p10.y*ffx;
        float c11 = p01.y*omx + p11.y*ffx;
        float c0  = c00*omy + c10*ffy;
        float c1  = c01*omy + c11*ffy;
        float intensity = c0*omz + c1*ffz;

        // ---- TF lookup: adjacent-pair LDS reads (ds_read2_b32) ----
        float xi = fminf(fmaxf(intensity, 0.0f), 1.0f) * 127.0f;
        int lo  = (int)floorf(xi);
        float tfr = xi - (float)lo;
        float omt = 1.0f - tfr;
        float cr  = tfR[lo]*omt + tfR[lo + 1]*tfr;
        float cg  = tfG[lo]*omt + tfG[lo + 1]*tfr;
        float cbb = tfB[lo]*omt + tfB[lo + 1]*tfr;
        float a   = tfA[lo]*omt + tfA[lo + 1]*tfr;

        if (sr_i == 1) {
            a = 1.0f - (1.0f - a);               // double rounding, as numpy
        } else {
            a = 1.0f - powf(1.0f - a, 1.0f / srf);
        }
        if (!valid) a = 0.0f;
        float one_m = 1.0f - a;

        // ---- 16-wide inclusive product scan of one_m ----
        float x = one_m;
        #pragma unroll
        for (int off = 1; off < 16; off <<= 1) {
            float y = __shfl_up(x, off);
            if (sub >= off) x *= y;
        }
        float ex = __shfl_up(x, 1);
        if (sub == 0) ex = 1.0f;                 // exclusive transmittance in chunk

        float wgt = (T_prev * ex) * a;
        rgb_r += wgt * cr;
        rgb_g += wgt * cg;
        rgb_b += wgt * cbb;
        acc   += wgt;
        if (valid && (a > 1e-3f)) hk_min = min(hk_min, k);

        float Tc = __shfl(x, (lane & 48) | 15);  // inclusive product at group end
        T_prev = T_prev * Tc;

        base += 16;
        // exit at T<1e-4: dropped tail <= 1e-4 per channel; first-hit is
        // guaranteed found (all a<=1e-3 over <=384 samples keeps T >= 0.68).
        bool active = hit && (base < ns) && (T_prev >= 1e-4f);
        if (__ballot(active) == 0ULL) break;
    }

    // ---- final reductions within each 16-lane group ----
    #pragma unroll
    for (int m = 8; m >= 1; m >>= 1) {
        rgb_r += __shfl_xor(rgb_r, m);
        rgb_g += __shfl_xor(rgb_g, m);
        rgb_b += __shfl_xor(rgb_b, m);
        acc   += __shfl_xor(acc,   m);
        hk_min = min(hk_min, __shfl_xor(hk_min, m));
    }

    if (sub == 0) {
        float depth = 1.0f;
        if (hk_min != 0x7FFFFFFF) {
            float tfh = entry + ((float)hk_min + 0.5f) * step;  // same expr as reference
            depth = (tfh - 0.1f) / 99.9f;
        }
        int oi = (w * RES_H + h) * 5;
        out[oi + 0] = rgb_r;
        out[oi + 1] = rgb_g;
        out[oi + 2] = rgb_b;
        out[oi + 3] = acc;
        out[oi + 4] = depth;
    }
}

extern "C" void kernel_launch(void* const* d_in, const int* in_sizes, int n_in,
                              void* d_out, int out_size, void* d_ws, size_t ws_size,
                              hipStream_t stream) {
    const float* vol = (const float*)d_in[0];
    const float* tf  = (const float*)d_in[1];
    const float* cam = (const float*)d_in[2];
    const int*   sr  = (const int*)d_in[3];
    float* out = (float*)d_out;
    float* rws = (float*)d_ws;          // 65536 * 8 floats = 2 MB scratch

    ray_setup_kernel<<<dim3(256), dim3(256), 0, stream>>>(cam, sr, rws);
    // 65536 rays, 16 lanes/ray, 16 rays/block -> 4096 blocks
    raycast_kernel<<<dim3(4096), dim3(256), 0, stream>>>(vol, tf, cam, sr, rws, out);
}

// Round 10
// 101.476 us; speedup vs baseline: 1.1206x; 1.0186x over previous
//
#include <hip/hip_runtime.h>
#include <math.h>

#define RES_W 256
#define RES_H 256
#define TF_RES 128

typedef float float2u __attribute__((ext_vector_type(2), aligned(4)));

// DPP row_shr:N with multiplicative-identity fill: y[lane] = (sub>=N) ? x[lane-N] : 1.0f
// (rows of 16 == our per-ray lane groups, so no cross-ray leakage)
#define DPP_SHR_ID(x, N) \
    __int_as_float(__builtin_amdgcn_update_dpp(0x3f800000, __float_as_int(x), 0x110 | (N), 0xF, 0xF, false))

// ---------- pass 1: per-ray setup (bit-exact basis / entry / step / ns) ----------
__global__ __launch_bounds__(256) void ray_setup_kernel(
    const float* __restrict__ cam_p,
    const int*   __restrict__ sr_p,
    float* __restrict__ rws)            // [65536][8]: dx,dy,dz,entry | step,nsf,hitf,0
{
    #pragma clang fp contract(off)
    const int ray = (int)blockIdx.x * 256 + (int)threadIdx.x;
    const int h = ray & 255;
    const int w = ray >> 8;

    const float cx = cam_p[0], cy = cam_p[1], cz = cam_p[2];
    const float srf = (float)sr_p[0];

    float nx = -cx, ny = -cy, nz = -cz;
    float fl = __fsqrt_rn((nx*nx + ny*ny) + nz*nz);
    float fx = nx / fl, fy = ny / fl, fz = nz / fl;
    float rxu = 0.0f - fz;
    float rzu = fx;
    float rl = __fsqrt_rn((rxu*rxu + 0.0f) + rzu*rzu);
    float rx = rxu / rl, rz = rzu / rl;
    float ux = 0.0f - rz*fy;
    float uy = rz*fx - rx*fz;
    float uz = rx*fy;

    const float ang32 = (float)((30.0 * 0.017453292519943295) * 0.5);
    const float tan_half = (float)tan((double)ang32);

    float uu = ((((float)w + 0.5f) / 256.0f) * 2.0f - 1.0f) * tan_half;
    float vv = ((((float)h + 0.5f) / 256.0f) * 2.0f - 1.0f) * tan_half;

    float dx = (fx + uu*rx) + vv*ux;
    float dy = (fy + 0.0f ) + vv*uy;
    float dz = (fz + uu*rz) + vv*uz;
    float dl = __fsqrt_rn((dx*dx + dy*dy) + dz*dz);
    dx = dx / dl; dy = dy / dl; dz = dz / dl;

    float ivx = 1.0f/dx, ivy = 1.0f/dy, ivz = 1.0f/dz;
    float tlx = (-1.0f - cx)*ivx, thx = (1.0f - cx)*ivx;
    float tly = (-1.0f - cy)*ivy, thy = (1.0f - cy)*ivy;
    float tlz = (-1.0f - cz)*ivz, thz = (1.0f - cz)*ivz;
    float tmin = fmaxf(fmaxf(fminf(tlx,thx), fminf(tly,thy)), fminf(tlz,thz));
    float tmax = fminf(fminf(fmaxf(tlx,thx), fmaxf(tly,thy)), fmaxf(tlz,thz));
    bool hit = (tmax >= 0.0f) && (tmin <= tmax);

    float entry = fmaxf(tmin, 0.1f);
    float dist  = hit ? fmaxf(tmax - entry, 0.0f) : 0.0f;
    float nsf   = fminf(fmaxf(ceilf(((dist * 0.5f) * 256.0f) * srf), 1.0f), 384.0f);
    float step  = dist / nsf;

    float4* o = (float4*)(rws + (size_t)ray * 8);
    o[0] = make_float4(dx, dy, dz, entry);
    o[1] = make_float4(step, nsf, hit ? 1.0f : 0.0f, 0.0f);
}

// ---------- pass 2: march. 16 lanes per ray, 4 rays/wave, chunk = 16 samples ----------
__global__ __launch_bounds__(256) void raycast_kernel(
    const float* __restrict__ vol,    // [256,256,256] x-major: idx = (x<<16)+(y<<8)+z
    const float* __restrict__ tf,     // [128,4]
    const float* __restrict__ cam_p,  // [3]
    const int*   __restrict__ sr_p,   // [1]
    const float* __restrict__ rws,    // per-ray setup from pass 1
    float* __restrict__ out)          // [256,256,5]
{
    #pragma clang fp contract(off)

    __shared__ float tfR[TF_RES + 1], tfG[TF_RES + 1], tfB[TF_RES + 1], tfA[TF_RES + 1];
    const int tid = (int)threadIdx.x;   // 0..255
    if (tid < TF_RES) {
        float4 e = ((const float4*)tf)[tid];
        tfR[tid] = e.x; tfG[tid] = e.y; tfB[tid] = e.z; tfA[tid] = e.w;
        if (tid == TF_RES - 1) {
            tfR[TF_RES] = e.x; tfG[TF_RES] = e.y; tfB[TF_RES] = e.z; tfA[TF_RES] = e.w;
        }
    }
    __syncthreads();

    const int lane = tid & 63;
    const int sub  = lane & 15;                // position within this ray's 16 lanes

    // 4096 blocks x 16 rays. XCD swizzle: block b -> XCD b%8 gets contiguous slab.
    const int b  = (int)blockIdx.x;
    const int sb = (b & 7) * 512 + (b >> 3);   // 0..4095
    const int ray = sb * 16 + (tid >> 4);      // 0..65535, h-major
    const int h = ray & 255;
    const int w = ray >> 8;

    const float cx = cam_p[0], cy = cam_p[1], cz = cam_p[2];
    const int   sr_i = sr_p[0];
    const float srf = (float)sr_i;

    const float4* rp = (const float4*)(rws + (size_t)ray * 8);
    float4 ra = rp[0];                          // dx,dy,dz,entry
    float4 rb = rp[1];                          // step,nsf,hitf
    const float dx = ra.x, dy = ra.y, dz = ra.z, entry = ra.w;
    const float step = rb.x;
    const int   ns   = (int)rb.y;
    const bool  hit  = (rb.z != 0.0f);

    float rgb_r = 0.0f, rgb_g = 0.0f, rgb_b = 0.0f, acc = 0.0f;  // per-lane partials
    float T_prev = 1.0f;          // ray transmittance entering current chunk
    int   hk_min = 0x7FFFFFFF;    // per-lane first-hit sample index

    for (int base = 0; ; ) {
        const int  k     = base + sub;
        const bool valid = hit && (k < ns);

        // ---- per-lane sample (bit-exact reference op order) ----
        float t  = entry + ((float)k + 0.5f) * step;
        float px = (cx + t*dx);
        float py = (cy + t*dy);
        float pz = (cz + t*dz);
        px = ((px * 0.5f) + 0.5f) * 255.0f;
        py = ((py * 0.5f) + 0.5f) * 255.0f;
        pz = ((pz * 0.5f) + 0.5f) * 255.0f;
        px = fminf(fmaxf(px, 0.0f), 255.0f);
        py = fminf(fmaxf(py, 0.0f), 255.0f);
        pz = fminf(fmaxf(pz, 0.0f), 255.0f);
        int x0 = (int)px, y0 = (int)py, z0 = (int)pz;   // >=0: trunc == floor
        float ffx = px - (float)x0;
        float ffy = py - (float)y0;
        float ffz = pz - (float)z0;
        int x1 = min(x0 + 1, 255);
        int y1 = min(y0 + 1, 255);
        int zb = min(z0, 254);               // z-pair base; z0==255 -> ffz==0 exactly
        int bx0 = x0 << 16, bx1 = x1 << 16;
        int by0 = y0 << 8,  by1 = y1 << 8;
        float2u p00 = *(const float2u*)(vol + (bx0 + by0 + zb));
        float2u p10 = *(const float2u*)(vol + (bx1 + by0 + zb));
        float2u p01 = *(const float2u*)(vol + (bx0 + by1 + zb));
        float2u p11 = *(const float2u*)(vol + (bx1 + by1 + zb));
        if (z0 == 255) {                     // tap z0 must read index 255 = pair.y
            p00.x = p00.y; p10.x = p10.y; p01.x = p01.y; p11.x = p11.y;
        }

        float omx = 1.0f - ffx, omy = 1.0f - ffy, omz = 1.0f - ffz;
        float c00 = p00.x*omx + p10.x*ffx;
        float c10 = p01.x*omx + p11.x*ffx;
        float c01 = p00.y*omx + p10.y*ffx;
        float c11 = p01.y*omx + p11.y*ffx;
        float c0  = c00*omy + c10*ffy;
        float c1  = c01*omy + c11*ffy;
        float intensity = c0*omz + c1*ffz;

        // ---- TF lookup: adjacent-pair LDS reads (ds_read2_b32) ----
        float xi = fminf(fmaxf(intensity, 0.0f), 1.0f) * 127.0f;
        int lo  = (int)xi;
        float tfr = xi - (float)lo;
        float omt = 1.0f - tfr;
        float cr  = tfR[lo]*omt + tfR[lo + 1]*tfr;
        float cg  = tfG[lo]*omt + tfG[lo + 1]*tfr;
        float cbb = tfB[lo]*omt + tfB[lo + 1]*tfr;
        float a   = tfA[lo]*omt + tfA[lo + 1]*tfr;

        if (sr_i == 1) {
            a = 1.0f - (1.0f - a);               // double rounding, as numpy
        } else {
            a = 1.0f - powf(1.0f - a, 1.0f / srf);
        }
        if (!valid) a = 0.0f;
        float one_m = 1.0f - a;

        // ---- 16-wide inclusive product scan via DPP row_shr (pure VALU) ----
        float x = one_m;
        x *= DPP_SHR_ID(x, 1);
        x *= DPP_SHR_ID(x, 2);
        x *= DPP_SHR_ID(x, 4);
        x *= DPP_SHR_ID(x, 8);
        float ex = DPP_SHR_ID(x, 1);             // exclusive; sub==0 gets 1.0

        float wgt = (T_prev * ex) * a;
        rgb_r += wgt * cr;
        rgb_g += wgt * cg;
        rgb_b += wgt * cbb;
        acc   += wgt;
        if (valid && (a > 1e-3f)) hk_min = min(hk_min, k);

        // group total = value at sub==15, broadcast within each 16-lane group:
        // ds_swizzle bit-mode offset 0x1F0: src = (lane & 0x10) | 0xF
        float Tc = __int_as_float(__builtin_amdgcn_ds_swizzle(__float_as_int(x), 0x1F0));
        T_prev = T_prev * Tc;

        base += 16;
        // exit at T<2e-3: dropped tail <= 2e-3 per channel (budget ok);
        // T<2e-3 implies some a>1e-3, so first-hit/depth already found.
        bool active = hit && (base < ns) && (T_prev >= 2e-3f);
        if (__ballot(active) == 0ULL) break;
    }

    // ---- final reductions within each 16-lane group ----
    #pragma unroll
    for (int m = 8; m >= 1; m >>= 1) {
        rgb_r += __shfl_xor(rgb_r, m);
        rgb_g += __shfl_xor(rgb_g, m);
        rgb_b += __shfl_xor(rgb_b, m);
        acc   += __shfl_xor(acc,   m);
        hk_min = min(hk_min, __shfl_xor(hk_min, m));
    }

    if (sub == 0) {
        float depth = 1.0f;
        if (hk_min != 0x7FFFFFFF) {
            float tfh = entry + ((float)hk_min + 0.5f) * step;  // same expr as reference
            depth = (tfh - 0.1f) / 99.9f;
        }
        int oi = (w * RES_H + h) * 5;
        out[oi + 0] = rgb_r;
        out[oi + 1] = rgb_g;
        out[oi + 2] = rgb_b;
        out[oi + 3] = acc;
        out[oi + 4] = depth;
    }
}

extern "C" void kernel_launch(void* const* d_in, const int* in_sizes, int n_in,
                              void* d_out, int out_size, void* d_ws, size_t ws_size,
                              hipStream_t stream) {
    const float* vol = (const float*)d_in[0];
    const float* tf  = (const float*)d_in[1];
    const float* cam = (const float*)d_in[2];
    const int*   sr  = (const int*)d_in[3];
    float* out = (float*)d_out;
    float* rws = (float*)d_ws;          // 65536 * 8 floats = 2 MB scratch

    ray_setup_kernel<<<dim3(256), dim3(256), 0, stream>>>(cam, sr, rws);
    // 65536 rays, 16 lanes/ray, 16 rays/block -> 4096 blocks
    raycast_kernel<<<dim3(4096), dim3(256), 0, stream>>>(vol, tf, cam, sr, rws, out);
}

// Round 11
// 99.925 us; speedup vs baseline: 1.1380x; 1.0155x over previous
//
#include <hip/hip_runtime.h>
#include <math.h>

#define RES_W 256
#define RES_H 256
#define TF_RES 128

typedef float float2u __attribute__((ext_vector_type(2), aligned(4)));

// One thread per ray, serial march with per-lane exec-mask termination.
// TA-throughput model: kernel cyc/CU ~= 2.1 * active lane-addresses/CU.
// Serial+mask minimizes addresses: ~7.2 samples * 4 z-pair taps per ray.
__global__ __launch_bounds__(64) void raycast_kernel(
    const float* __restrict__ vol,    // [256,256,256] x-major: idx = (x<<16)+(y<<8)+z
    const float* __restrict__ tf,     // [128,4]
    const float* __restrict__ cam_p,  // [3]
    const int*   __restrict__ sr_p,   // [1]
    float* __restrict__ out)          // [256,256,5]  idx = (w*256+h)*5+c
{
    #pragma clang fp contract(off)

    // 129-entry SoA TF tables: [128] dups [127] so (lo,lo+1) is always an
    // adjacent-dword pair -> ds_read2_b32; exact at the lo==127 edge.
    __shared__ float tfR[TF_RES + 1], tfG[TF_RES + 1], tfB[TF_RES + 1], tfA[TF_RES + 1];
    const int tid = (int)threadIdx.x;          // 0..63
    {
        const float4* tf4 = (const float4*)tf;
        float4 e0 = tf4[tid];
        float4 e1 = tf4[tid + 64];
        tfR[tid] = e0.x; tfG[tid] = e0.y; tfB[tid] = e0.z; tfA[tid] = e0.w;
        tfR[tid + 64] = e1.x; tfG[tid + 64] = e1.y; tfB[tid + 64] = e1.z; tfA[tid + 64] = e1.w;
        if (tid == 63) {
            tfR[TF_RES] = e1.x; tfG[TF_RES] = e1.y; tfB[TF_RES] = e1.z; tfA[TF_RES] = e1.w;
        }
    }
    __syncthreads();

    // 1024 blocks x 64 threads; wave = 8x8 pixel tile (coherent gather front).
    // XCD swizzle: block b -> XCD b%8 gets a contiguous image slab for L2 locality.
    const int b    = (int)blockIdx.x;          // 0..1023
    const int tile = (b % 8) * 128 + (b / 8);  // 0..1023
    const int tile_h = tile % 32;
    const int tile_w = tile / 32;
    const int h = tile_h * 8 + (tid % 8);      // H index (v axis)
    const int w = tile_w * 8 + (tid / 8);      // W index (u axis)

    const float cx = cam_p[0], cy = cam_p[1], cz = cam_p[2];
    const int   sr_i = sr_p[0];
    const float srf = (float)sr_i;

    // ---- camera basis, fp32, numpy op order, no FMA (bit-matches reference) ----
    float nx = -cx, ny = -cy, nz = -cz;
    float fl = __fsqrt_rn((nx*nx + ny*ny) + nz*nz);
    float fx = nx / fl, fy = ny / fl, fz = nz / fl;
    float rxu = 0.0f - fz;
    float rzu = fx;
    float rl = __fsqrt_rn((rxu*rxu + 0.0f) + rzu*rzu);
    float rx = rxu / rl, rz = rzu / rl;
    float ux = 0.0f - rz*fy;
    float uy = rz*fx - rx*fz;
    float uz = rx*fy;

    const float ang32 = (float)((30.0 * 0.017453292519943295) * 0.5);
    const float tan_half = (float)tan((double)ang32);

    float uu = ((((float)w + 0.5f) / 256.0f) * 2.0f - 1.0f) * tan_half;
    float vv = ((((float)h + 0.5f) / 256.0f) * 2.0f - 1.0f) * tan_half;

    float dx = (fx + uu*rx) + vv*ux;
    float dy = (fy + 0.0f ) + vv*uy;
    float dz = (fz + uu*rz) + vv*uz;
    float dl = __fsqrt_rn((dx*dx + dy*dy) + dz*dz);
    dx = dx / dl; dy = dy / dl; dz = dz / dl;

    float ivx = 1.0f/dx, ivy = 1.0f/dy, ivz = 1.0f/dz;
    float tlx = (-1.0f - cx)*ivx, thx = (1.0f - cx)*ivx;
    float tly = (-1.0f - cy)*ivy, thy = (1.0f - cy)*ivy;
    float tlz = (-1.0f - cz)*ivz, thz = (1.0f - cz)*ivz;
    float tmin = fmaxf(fmaxf(fminf(tlx,thx), fminf(tly,thy)), fminf(tlz,thz));
    float tmax = fminf(fminf(fmaxf(tlx,thx), fmaxf(tly,thy)), fmaxf(tlz,thz));
    bool hit = (tmax >= 0.0f) && (tmin <= tmax);

    float entry = fmaxf(tmin, 0.1f);
    float dist  = hit ? fmaxf(tmax - entry, 0.0f) : 0.0f;
    float nsf   = fminf(fmaxf(ceilf(((dist * 0.5f) * 256.0f) * srf), 1.0f), 384.0f);
    int   ns    = (int)nsf;
    float step  = dist / nsf;

    float rgb_r = 0.0f, rgb_g = 0.0f, rgb_b = 0.0f, acc = 0.0f;
    float Texcl = 1.0f;
    float depth = 1.0f;
    bool  found = false;
    bool  done  = !hit;
    int   k = 0;

    for (;;) {
        if (!done) {
            // ---- sample k (bit-exact reference op order) ----
            float t  = entry + ((float)k + 0.5f) * step;
            float px = (cx + t*dx);
            float py = (cy + t*dy);
            float pz = (cz + t*dz);
            px = ((px * 0.5f) + 0.5f) * 255.0f;
            py = ((py * 0.5f) + 0.5f) * 255.0f;
            pz = ((pz * 0.5f) + 0.5f) * 255.0f;
            px = fminf(fmaxf(px, 0.0f), 255.0f);
            py = fminf(fmaxf(py, 0.0f), 255.0f);
            pz = fminf(fmaxf(pz, 0.0f), 255.0f);
            int x0 = (int)px, y0 = (int)py, z0 = (int)pz;   // >=0: trunc == floor
            float ffx = px - (float)x0;
            float ffy = py - (float)y0;
            float ffz = pz - (float)z0;
            int x1 = min(x0 + 1, 255);
            int y1 = min(y0 + 1, 255);
            int zb = min(z0, 254);            // z-pair base; z0==255 -> ffz==0 exactly
            int bx0 = x0 << 16, bx1 = x1 << 16;
            int by0 = y0 << 8,  by1 = y1 << 8;
            float2u p00 = *(const float2u*)(vol + (bx0 + by0 + zb));
            float2u p10 = *(const float2u*)(vol + (bx1 + by0 + zb));
            float2u p01 = *(const float2u*)(vol + (bx0 + by1 + zb));
            float2u p11 = *(const float2u*)(vol + (bx1 + by1 + zb));
            if (z0 == 255) {                  // tap z0 must read index 255 = pair.y
                p00.x = p00.y; p10.x = p10.y; p01.x = p01.y; p11.x = p11.y;
            }

            float omx = 1.0f - ffx, omy = 1.0f - ffy, omz = 1.0f - ffz;
            float c00 = p00.x*omx + p10.x*ffx;
            float c10 = p01.x*omx + p11.x*ffx;
            float c01 = p00.y*omx + p10.y*ffx;
            float c11 = p01.y*omx + p11.y*ffx;
            float c0  = c00*omy + c10*ffy;
            float c1  = c01*omy + c11*ffy;
            float intensity = c0*omz + c1*ffz;

            // ---- TF lookup (adjacent-pair LDS reads) ----
            float xi = fminf(fmaxf(intensity, 0.0f), 1.0f) * 127.0f;
            int lo  = (int)xi;
            float tfr = xi - (float)lo;
            float omt = 1.0f - tfr;
            float cr  = tfR[lo]*omt + tfR[lo + 1]*tfr;
            float cg  = tfG[lo]*omt + tfG[lo + 1]*tfr;
            float cbb = tfB[lo]*omt + tfB[lo + 1]*tfr;
            float a   = tfA[lo]*omt + tfA[lo + 1]*tfr;

            if (sr_i == 1) {
                a = 1.0f - (1.0f - a);            // double rounding, as numpy
            } else {
                a = 1.0f - powf(1.0f - a, 1.0f / srf);
            }
            float one_m = 1.0f - a;
            float wgt = Texcl * a;
            rgb_r += wgt * cr;
            rgb_g += wgt * cg;
            rgb_b += wgt * cbb;
            acc   += wgt;
            if (!found && a > 1e-3f) {
                found = true;
                depth = (t - 0.1f) / 99.9f;
            }
            Texcl = Texcl * one_m;
            k++;
            // T<2e-3 guarantees some a>0.016>1e-3 occurred, so depth is set;
            // dropped tail contributes <= Texcl < 2e-3 per channel (budget ok).
            done = (k >= ns) || (Texcl < 2e-3f);
        }
        if (__ballot(!done) == 0ULL) break;
    }

    {
        int oi = (w * RES_H + h) * 5;
        out[oi + 0] = rgb_r;
        out[oi + 1] = rgb_g;
        out[oi + 2] = rgb_b;
        out[oi + 3] = acc;
        out[oi + 4] = depth;
    }
}

extern "C" void kernel_launch(void* const* d_in, const int* in_sizes, int n_in,
                              void* d_out, int out_size, void* d_ws, size_t ws_size,
                              hipStream_t stream) {
    const float* vol = (const float*)d_in[0];
    const float* tf  = (const float*)d_in[1];
    const float* cam = (const float*)d_in[2];
    const int*   sr  = (const int*)d_in[3];
    float* out = (float*)d_out;

    raycast_kernel<<<dim3(1024), dim3(64), 0, stream>>>(vol, tf, cam, sr, out);
}